// Round 5
// baseline (277.011 us; speedup 1.0000x reference)
//
#include <hip/hip_runtime.h>
#include <math.h>

#define NH 8
#define NP 4
#define DD 64
#define DM 512

typedef unsigned short u16;
typedef unsigned int u32;

using frag_ab = __attribute__((ext_vector_type(8))) short;  // 8 bf16 (4 VGPRs)
using f32x4   = __attribute__((ext_vector_type(4))) float;  // 4 fp32 acc

__device__ __forceinline__ u16 f2b(float f) {               // fp32 -> bf16 (RNE)
    u32 u = __float_as_uint(f);
    u32 r = (u + 0x7FFFu + ((u >> 16) & 1u)) >> 16;
    return (u16)r;
}

#define GLOBAL_AS __attribute__((address_space(1)))
#define LDS_AS    __attribute__((address_space(3)))
__device__ __forceinline__ void async_copy16(void* lds, const void* g) {
    __builtin_amdgcn_global_load_lds((const GLOBAL_AS u32*)g, (LDS_AS u32*)lds, 16, 0, 0);
}

// ---------------------------------------------------------------------------
// Merged projection GEMM.  BM=128, BN=256, BK=32, 4 waves (wave tile 64x128).
//   blockIdx.y < 3 : C = qb @ Wcat1^T + bcat1  (N=576; cols<512 -> q_ws bf16,
//                    cols>=512 -> offlog f32 ld64; tail frags skipped)
//   blockIdx.y >= 3: C = kvb @ Wcat2^T + bcat2 (N=1024 -> kv_ws bf16 ld1024)
// ---------------------------------------------------------------------------
__global__ __launch_bounds__(256) void proj_gemm(
    const u16* __restrict__ qb, const u16* __restrict__ kvb,
    const u16* __restrict__ Wcat1, const u16* __restrict__ Wcat2,
    const float* __restrict__ bcat1, const float* __restrict__ bcat2,
    u16* __restrict__ q_ws, float* __restrict__ offlog,
    u16* __restrict__ kv_ws)
{
    constexpr int BM = 128, BK = 32, BN = 256;
    __shared__ u16 sA[BM * BK];
    __shared__ u16 sB[BN * BK];

    const int tid  = threadIdx.x;
    const int wave = tid >> 6;
    const int lane = tid & 63;
    const int m0 = blockIdx.x * BM;
    const bool is_q = blockIdx.y < 3;
    const int n0 = (is_q ? blockIdx.y : blockIdx.y - 3) * BN;
    const int Ncur = is_q ? 576 : 1024;
    const u16* __restrict__ A    = is_q ? qb : kvb;
    const u16* __restrict__ Wt   = is_q ? Wcat1 : Wcat2;
    const float* __restrict__ bias = is_q ? bcat1 : bcat2;

    const int wrow = 64 * (wave >> 1);
    const int wcol = 128 * (wave & 1);

    f32x4 acc[4][8] = {};
    const int lr = lane & 15;
    const int kg = lane >> 4;

    for (int kt = 0; kt < 16; ++kt) {
        const int k0 = kt << 5;
#pragma unroll
        for (int i = 0; i < 2; ++i) {             // A: 8 KB = 8 groups
            int grp = i * 4 + wave;
            int c   = grp * 64 + lane;
            const u16* g = A + (size_t)(m0 + (c >> 2)) * DM + k0 + ((c & 3) << 3);
            async_copy16(&sA[grp * 512], g);
        }
#pragma unroll
        for (int i = 0; i < 4; ++i) {             // B: 16 KB = 16 groups
            int grp = i * 4 + wave;
            int c   = grp * 64 + lane;
            const u16* g = Wt + (size_t)(n0 + (c >> 2)) * DM + k0 + ((c & 3) << 3);
            async_copy16(&sB[grp * 512], g);
        }
        __syncthreads();

        frag_ab af[4], bfr[8];
#pragma unroll
        for (int i = 0; i < 4; ++i)
            af[i] = *(const frag_ab*)&sA[(wrow + i * 16 + lr) * 32 + kg * 8];
#pragma unroll
        for (int j = 0; j < 8; ++j)
            bfr[j] = *(const frag_ab*)&sB[(wcol + j * 16 + lr) * 32 + kg * 8];
#pragma unroll
        for (int i = 0; i < 4; ++i)
#pragma unroll
            for (int j = 0; j < 8; ++j)
                acc[i][j] = __builtin_amdgcn_mfma_f32_16x16x32_bf16(
                    af[i], bfr[j], acc[i][j], 0, 0, 0);
        __syncthreads();
    }

    const int crow0 = (lane >> 4) * 4;
#pragma unroll
    for (int i = 0; i < 4; ++i) {
#pragma unroll
        for (int j = 0; j < 8; ++j) {
            const int colbase = n0 + wcol + j * 16;
            if (colbase >= Ncur) continue;        // wave-uniform tail skip
            const int col = colbase + lr;
            const float bv = bias[col];
#pragma unroll
            for (int r = 0; r < 4; ++r) {
                const int row = m0 + wrow + i * 16 + crow0 + r;
                const float val = acc[i][j][r] + bv;
                if (!is_q)
                    kv_ws[(size_t)row * 1024 + col] = f2b(val);
                else if (colbase < 512)
                    q_ws[(size_t)row * 512 + col] = f2b(val);
                else
                    offlog[(size_t)row * 64 + (col - 512)] = val;
            }
        }
    }
}

// ---------------------------------------------------------------------------
// Output GEMM: C(f32) = A(bf16,M x512) @ Wob^T + bo.  BN=256, grid.y=2.
// ---------------------------------------------------------------------------
__global__ __launch_bounds__(256) void out_gemm(
    const u16* __restrict__ A, const u16* __restrict__ Wt,
    const float* __restrict__ bias, float* __restrict__ C)
{
    constexpr int BM = 128, BK = 32, BN = 256;
    __shared__ u16 sA[BM * BK];
    __shared__ u16 sB[BN * BK];

    const int tid  = threadIdx.x;
    const int wave = tid >> 6;
    const int lane = tid & 63;
    const int m0 = blockIdx.x * BM;
    const int n0 = blockIdx.y * BN;

    const int wrow = 64 * (wave >> 1);
    const int wcol = 128 * (wave & 1);

    f32x4 acc[4][8] = {};
    const int lr = lane & 15;
    const int kg = lane >> 4;

    for (int kt = 0; kt < 16; ++kt) {
        const int k0 = kt << 5;
#pragma unroll
        for (int i = 0; i < 2; ++i) {
            int grp = i * 4 + wave;
            int c   = grp * 64 + lane;
            const u16* g = A + (size_t)(m0 + (c >> 2)) * DM + k0 + ((c & 3) << 3);
            async_copy16(&sA[grp * 512], g);
        }
#pragma unroll
        for (int i = 0; i < 4; ++i) {
            int grp = i * 4 + wave;
            int c   = grp * 64 + lane;
            const u16* g = Wt + (size_t)(n0 + (c >> 2)) * DM + k0 + ((c & 3) << 3);
            async_copy16(&sB[grp * 512], g);
        }
        __syncthreads();

        frag_ab af[4], bfr[8];
#pragma unroll
        for (int i = 0; i < 4; ++i)
            af[i] = *(const frag_ab*)&sA[(wrow + i * 16 + lr) * 32 + kg * 8];
#pragma unroll
        for (int j = 0; j < 8; ++j)
            bfr[j] = *(const frag_ab*)&sB[(wcol + j * 16 + lr) * 32 + kg * 8];
#pragma unroll
        for (int i = 0; i < 4; ++i)
#pragma unroll
            for (int j = 0; j < 8; ++j)
                acc[i][j] = __builtin_amdgcn_mfma_f32_16x16x32_bf16(
                    af[i], bfr[j], acc[i][j], 0, 0, 0);
        __syncthreads();
    }

    const int crow0 = (lane >> 4) * 4;
#pragma unroll
    for (int i = 0; i < 4; ++i) {
#pragma unroll
        for (int j = 0; j < 8; ++j) {
            const int col = n0 + wcol + j * 16 + lr;
            const float bv = bias[col];
#pragma unroll
            for (int r = 0; r < 4; ++r) {
                const int row = m0 + wrow + i * 16 + crow0 + r;
                C[(size_t)row * 512 + col] = acc[i][j][r] + bv;
            }
        }
    }
}

// ---------------------------------------------------------------------------
// One-shot prep: cast q_in/kv_in f32->bf16, pack all weights (bf16 concats),
// concat biases.  Linear tid over float4 granules.
//   Wcat1 = [Wq; Woff; Wa] (576x512, alloc 768)   bcat1 = [bq; boff; ba]
//   Wcat2 = [Wk; Wv]       (1024x512)             bcat2 = [bk; bv]
//   Wob   = Wo
// ---------------------------------------------------------------------------
__global__ __launch_bounds__(256) void prep_all(
    const float* __restrict__ q_in, const float* __restrict__ kv_in,
    const float* __restrict__ Wq, const float* __restrict__ Woff,
    const float* __restrict__ Wa, const float* __restrict__ Wk,
    const float* __restrict__ Wv, const float* __restrict__ Wo,
    const float* __restrict__ bq, const float* __restrict__ boff,
    const float* __restrict__ ba, const float* __restrict__ bk,
    const float* __restrict__ bv,
    u16* __restrict__ qb, u16* __restrict__ kvb,
    u16* __restrict__ Wcat1, u16* __restrict__ Wcat2, u16* __restrict__ Wob,
    float* __restrict__ bcat1, float* __restrict__ bcat2, int n4)
{
    const int W4  = 65536;   // 512*512/4
    const int W4s = 4096;    // 32*512/4
    int tid = blockIdx.x * 256 + threadIdx.x;
    if (tid < 2 * n4 + 4 * W4 + 2 * W4s) {
        const float* src; u16* dst; int off;
        int t = tid;
        if (t < n4)                    { src = q_in;  dst = qb;              off = t; }
        else if ((t -= n4) < n4)       { src = kv_in; dst = kvb;             off = t; }
        else if ((t -= n4) < W4)       { src = Wq;    dst = Wcat1;           off = t; }
        else if ((t -= W4) < W4s)      { src = Woff;  dst = Wcat1 + 262144;  off = t; }
        else if ((t -= W4s) < W4s)     { src = Wa;    dst = Wcat1 + 278528;  off = t; }
        else if ((t -= W4s) < W4)      { src = Wk;    dst = Wcat2;           off = t; }
        else if ((t -= W4) < W4)       { src = Wv;    dst = Wcat2 + 262144;  off = t; }
        else                           { src = Wo;    dst = Wob;             off = t - W4; }
        float4 v = ((const float4*)src)[off];
        ushort4 o;
        o.x = f2b(v.x); o.y = f2b(v.y); o.z = f2b(v.z); o.w = f2b(v.w);
        ((ushort4*)dst)[off] = o;
    } else {
        int j = tid - (2 * n4 + 4 * W4 + 2 * W4s);
        if (j < 576) {
            bcat1[j] = (j < 512) ? bq[j] : (j < 544 ? boff[j - 512] : ba[j - 544]);
        } else if (j < 1600) {
            int j2 = j - 576;
            bcat2[j2] = (j2 < 512) ? bk[j2] : bv[j2 - 512];
        }
    }
}

// ---------------------------------------------------------------------------
// Banded deformable attention. One wave per (b, h, 16-query block).
// k|v fused buffer: row stride 1024, k at cols 0..511, v at 512..1023.
// ---------------------------------------------------------------------------
__global__ __launch_bounds__(256) void deform_attn_band(
    const u16* __restrict__ q, const u16* __restrict__ kv,
    const float* __restrict__ offlog, u16* __restrict__ out, int B, int L)
{
    __shared__ u16  sVt[4][64 * 40];
    __shared__ float sS[4][16 * 36];
    __shared__ float sW[4][16 * 36];

    const int wave = threadIdx.x >> 6;
    const int lane = threadIdx.x & 63;
    const int gw = blockIdx.x * 4 + wave;     // over B*NH*(L/16)
    const int nlb = L >> 4;
    const int lblk = gw % nlb;
    const int bh = gw / nlb;
    const int h = bh % NH;
    const int b = bh / NH;
    const int l0 = lblk << 4;

    u16*  __restrict__ vt = sVt[wave];
    float* __restrict__ Ss = sS[wave];
    float* __restrict__ Ws = sW[wave];

    const size_t brow = (size_t)b * L;
    const int headoff = h * DD;

    const int l_loc = lane >> 2, p = lane & 3;
    const size_t obase = (brow + l0 + l_loc) * 64 + h * 4 + p;
    const float offv  = offlog[obase];
    const float logit = offlog[obase + 32];

    const int fr = lane & 15, kg = lane >> 4;

    const u16* qrow = q + (brow + l0 + fr) * DM + headoff;
    frag_ab qf0 = *(const frag_ab*)(qrow + kg * 8);
    frag_ab qf1 = *(const frag_ab*)(qrow + kg * 8 + 32);

    frag_ab kf[2][2];
#pragma unroll
    for (int jf = 0; jf < 2; ++jf) {
        int rr = l0 - 8 + jf * 16 + fr;
        rr = min(max(rr, 0), L - 1);
        const u16* krow = kv + (brow + rr) * 1024 + headoff;
        kf[jf][0] = *(const frag_ab*)(krow + kg * 8);
        kf[jf][1] = *(const frag_ab*)(krow + kg * 8 + 32);
    }

    const int vr = lane & 31, vd0 = (lane >> 5) * 32;
    int vrr = min(max(l0 - 8 + vr, 0), L - 1);
    const u16* vrow = kv + (brow + vrr) * 1024 + 512 + headoff + vd0;
    frag_ab vl[4];
#pragma unroll
    for (int i = 0; i < 4; ++i)
        vl[i] = *(const frag_ab*)(vrow + i * 8);

    f32x4 accS[2] = {};
#pragma unroll
    for (int jf = 0; jf < 2; ++jf) {
        accS[jf] = __builtin_amdgcn_mfma_f32_16x16x32_bf16(qf0, kf[jf][0], accS[jf], 0, 0, 0);
        accS[jf] = __builtin_amdgcn_mfma_f32_16x16x32_bf16(qf1, kf[jf][1], accS[jf], 0, 0, 0);
    }

#pragma unroll
    for (int i = 0; i < 4; ++i)
#pragma unroll
        for (int j = 0; j < 8; ++j)
            vt[(vd0 + i * 8 + j) * 40 + vr] = (u16)vl[i][j];

#pragma unroll
    for (int jf = 0; jf < 2; ++jf)
#pragma unroll
        for (int r = 0; r < 4; ++r)
            Ss[(kg * 4 + r) * 36 + jf * 16 + fr] = accS[jf][r];

#pragma unroll
    for (int i = 0; i < 9; ++i)
        Ws[lane + 64 * i] = 0.f;

    __syncthreads();

    float pos = fminf(fmaxf((float)(l0 + l_loc) + offv, 0.f), (float)(L - 1));
    float ff = floorf(pos);
    int i0 = (int)ff;
    float fw = pos - ff;
    int c0 = i0 - (l0 - 8);
    c0 = min(max(c0, 0), 30);
    float S0 = Ss[l_loc * 36 + c0];
    float S1 = Ss[l_loc * 36 + c0 + 1];
    float t = (S0 + fw * (S1 - S0)) * 0.125f + logit;
    float m1 = fmaxf(t, __shfl_xor(t, 1));
    float mx = fmaxf(m1, __shfl_xor(m1, 2));
    float e = __expf(t - mx);
    float s1 = e + __shfl_xor(e, 1);
    float ssum = s1 + __shfl_xor(s1, 2);
    float wgt = e * __builtin_amdgcn_rcpf(ssum);
    atomicAdd(&Ws[l_loc * 36 + c0], (1.f - fw) * wgt);
    atomicAdd(&Ws[l_loc * 36 + c0 + 1], fw * wgt);

    __syncthreads();

    float4 w0 = *(const float4*)&Ws[fr * 36 + kg * 8];
    float4 w1 = *(const float4*)&Ws[fr * 36 + kg * 8 + 4];
    frag_ab wf;
    wf[0] = (short)f2b(w0.x); wf[1] = (short)f2b(w0.y);
    wf[2] = (short)f2b(w0.z); wf[3] = (short)f2b(w0.w);
    wf[4] = (short)f2b(w1.x); wf[5] = (short)f2b(w1.y);
    wf[6] = (short)f2b(w1.z); wf[7] = (short)f2b(w1.w);

#pragma unroll
    for (int md = 0; md < 4; ++md) {
        frag_ab af = *(const frag_ab*)&vt[(md * 16 + fr) * 40 + kg * 8];
        f32x4 o = {};
        o = __builtin_amdgcn_mfma_f32_16x16x32_bf16(af, wf, o, 0, 0, 0);
        ushort4 pk;
        pk.x = f2b(o[0]); pk.y = f2b(o[1]); pk.z = f2b(o[2]); pk.w = f2b(o[3]);
        *(ushort4*)&out[(brow + l0 + fr) * DM + headoff + md * 16 + kg * 4] = pk;
    }
}

// ---------------------------------------------------------------------------
extern "C" void kernel_launch(void* const* d_in, const int* in_sizes, int n_in,
                              void* d_out, int out_size, void* d_ws, size_t ws_size,
                              hipStream_t stream) {
    const float* q_in  = (const float*)d_in[0];
    const float* kv_in = (const float*)d_in[1];
    const float* Wq = (const float*)d_in[2];  const float* bq = (const float*)d_in[3];
    const float* Wk = (const float*)d_in[4];  const float* bk = (const float*)d_in[5];
    const float* Wv = (const float*)d_in[6];  const float* bv = (const float*)d_in[7];
    const float* Woff=(const float*)d_in[8];  const float* boff=(const float*)d_in[9];
    const float* Wa = (const float*)d_in[10]; const float* ba = (const float*)d_in[11];
    const float* Wo = (const float*)d_in[12]; const float* bo = (const float*)d_in[13];

    const int M = in_sizes[0] / DM;     // B*L = 16384
    const int L = 4096;
    const int B = M / L;

    char* p = (char*)d_ws;
    u16* qb     = (u16*)p;               p += (size_t)M * DM * 2;     // attn out later
    u16* kvb    = (u16*)p;               p += (size_t)M * DM * 2;
    u16* Wcat1  = (u16*)p;               p += (size_t)768 * DM * 2;   // 576 used; pad for OOB staging
    u16* Wcat2  = (u16*)p;               p += (size_t)1024 * DM * 2;
    u16* Wob    = (u16*)p;               p += (size_t)DM * DM * 2;
    float* bcat1= (float*)p;             p += 640 * 4;
    float* bcat2= (float*)p;             p += 1024 * 4;
    u16* q_ws   = (u16*)p;               p += (size_t)M * DM * 2;
    u16* kv_ws  = (u16*)p;               p += (size_t)M * 1024 * 2;   // k|v fused
    float* offlog = (float*)p;           p += (size_t)M * 64 * 4;

    dim3 blk(256);
    const int n4 = (M * DM) / 4;
    const int prep_threads = 2 * n4 + 4 * 65536 + 2 * 4096 + 1600;

    hipLaunchKernelGGL(prep_all, dim3((prep_threads + 255) / 256), blk, 0, stream,
                       q_in, kv_in, Wq, Woff, Wa, Wk, Wv, Wo,
                       bq, boff, ba, bk, bv,
                       qb, kvb, Wcat1, Wcat2, Wob, bcat1, bcat2, n4);

    // merged projections: y<3 -> q/off/a (N=576), y>=3 -> k|v (N=1024)
    hipLaunchKernelGGL(proj_gemm, dim3(M / 128, 7), blk, 0, stream,
                       qb, kvb, Wcat1, Wcat2, bcat1, bcat2,
                       q_ws, offlog, kv_ws);

    // banded attention: 1 wave per (b,h,16 queries); out -> qb
    int nwaves = B * NH * (L / 16);
    hipLaunchKernelGGL(deform_attn_band, dim3(nwaves / 4), blk, 0, stream,
                       q_ws, kv_ws, offlog, qb, B, L);

    // output projection -> fp32 d_out
    hipLaunchKernelGGL(out_gemm, dim3(M / 128, 2), blk, 0, stream,
                       qb, Wob, bo, (float*)d_out);
}

// Round 6
// 230.661 us; speedup vs baseline: 1.2009x; 1.2009x over previous
//
#include <hip/hip_runtime.h>
#include <math.h>

#define NH 8
#define NP 4
#define DD 64
#define DM 512

typedef unsigned short u16;
typedef unsigned int u32;

using frag_ab = __attribute__((ext_vector_type(8))) short;  // 8 bf16 (4 VGPRs)
using f32x4   = __attribute__((ext_vector_type(4))) float;  // 4 fp32 acc

__device__ __forceinline__ u16 f2b(float f) {               // fp32 -> bf16 (RNE)
    u32 u = __float_as_uint(f);
    u32 r = (u + 0x7FFFu + ((u >> 16) & 1u)) >> 16;
    return (u16)r;
}

#define GLOBAL_AS __attribute__((address_space(1)))
#define LDS_AS    __attribute__((address_space(3)))
__device__ __forceinline__ void async_copy16(void* lds, const void* g) {
    __builtin_amdgcn_global_load_lds((const GLOBAL_AS u32*)g, (LDS_AS u32*)lds, 16, 0, 0);
}

// ---------------------------------------------------------------------------
// Merged projection GEMM.  BM=128, BN=256, BK=32, 512 threads = 8 waves,
// wave tile 64x64 (acc[4][4] = 64 AGPRs -> no occupancy cliff).
//   blockIdx.y < 3 : C = qb @ Wcat1^T + bcat1  (N=576; cols<512 -> q_ws bf16,
//                    cols>=512 -> offlog f32 ld64; tail frags skipped)
//   blockIdx.y >= 3: C = kvb @ Wcat2^T + bcat2 (N=1024 -> kv_ws bf16 ld1024)
// ---------------------------------------------------------------------------
__global__ __launch_bounds__(512) void proj_gemm(
    const u16* __restrict__ qb, const u16* __restrict__ kvb,
    const u16* __restrict__ Wcat1, const u16* __restrict__ Wcat2,
    const float* __restrict__ bcat1, const float* __restrict__ bcat2,
    u16* __restrict__ q_ws, float* __restrict__ offlog,
    u16* __restrict__ kv_ws)
{
    constexpr int BM = 128, BK = 32, BN = 256;
    __shared__ u16 sA[BM * BK];
    __shared__ u16 sB[BN * BK];

    const int tid  = threadIdx.x;
    const int wave = tid >> 6;      // 0..7
    const int lane = tid & 63;
    const int m0 = blockIdx.x * BM;
    const bool is_q = blockIdx.y < 3;
    const int n0 = (is_q ? blockIdx.y : blockIdx.y - 3) * BN;
    const int Ncur = is_q ? 576 : 1024;
    const u16* __restrict__ A    = is_q ? qb : kvb;
    const u16* __restrict__ Wt   = is_q ? Wcat1 : Wcat2;
    const float* __restrict__ bias = is_q ? bcat1 : bcat2;

    const int wrow = 64 * (wave >> 2);   // 0 / 64
    const int wcol = 64 * (wave & 3);    // 0 / 64 / 128 / 192

    f32x4 acc[4][4] = {};
    const int lr = lane & 15;
    const int kg = lane >> 4;

    for (int kt = 0; kt < 16; ++kt) {
        const int k0 = kt << 5;
        {   // A: 8 KB = 8 groups, one per wave
            int c = wave * 64 + lane;
            const u16* g = A + (size_t)(m0 + (c >> 2)) * DM + k0 + ((c & 3) << 3);
            async_copy16(&sA[wave * 512], g);
        }
#pragma unroll
        for (int i = 0; i < 2; ++i) {     // B: 16 KB = 16 groups, two per wave
            int grp = i * 8 + wave;
            int c   = grp * 64 + lane;
            const u16* g = Wt + (size_t)(n0 + (c >> 2)) * DM + k0 + ((c & 3) << 3);
            async_copy16(&sB[grp * 512], g);
        }
        __syncthreads();

        frag_ab af[4], bfr[4];
#pragma unroll
        for (int i = 0; i < 4; ++i)
            af[i] = *(const frag_ab*)&sA[(wrow + i * 16 + lr) * 32 + kg * 8];
#pragma unroll
        for (int j = 0; j < 4; ++j)
            bfr[j] = *(const frag_ab*)&sB[(wcol + j * 16 + lr) * 32 + kg * 8];
#pragma unroll
        for (int i = 0; i < 4; ++i)
#pragma unroll
            for (int j = 0; j < 4; ++j)
                acc[i][j] = __builtin_amdgcn_mfma_f32_16x16x32_bf16(
                    af[i], bfr[j], acc[i][j], 0, 0, 0);
        __syncthreads();
    }

    const int crow0 = (lane >> 4) * 4;
#pragma unroll
    for (int i = 0; i < 4; ++i) {
#pragma unroll
        for (int j = 0; j < 4; ++j) {
            const int colbase = n0 + wcol + j * 16;
            if (colbase >= Ncur) continue;        // wave-uniform tail skip
            const int col = colbase + lr;
            const float bv = bias[col];
#pragma unroll
            for (int r = 0; r < 4; ++r) {
                const int row = m0 + wrow + i * 16 + crow0 + r;
                const float val = acc[i][j][r] + bv;
                if (!is_q)
                    kv_ws[(size_t)row * 1024 + col] = f2b(val);
                else if (colbase < 512)
                    q_ws[(size_t)row * 512 + col] = f2b(val);
                else
                    offlog[(size_t)row * 64 + (col - 512)] = val;
            }
        }
    }
}

// ---------------------------------------------------------------------------
// Output GEMM: C(f32) = A(bf16,Mx512) @ Wob^T + bo.  Same 512-thread shape.
// ---------------------------------------------------------------------------
__global__ __launch_bounds__(512) void out_gemm(
    const u16* __restrict__ A, const u16* __restrict__ Wt,
    const float* __restrict__ bias, float* __restrict__ C)
{
    constexpr int BM = 128, BK = 32, BN = 256;
    __shared__ u16 sA[BM * BK];
    __shared__ u16 sB[BN * BK];

    const int tid  = threadIdx.x;
    const int wave = tid >> 6;
    const int lane = tid & 63;
    const int m0 = blockIdx.x * BM;
    const int n0 = blockIdx.y * BN;

    const int wrow = 64 * (wave >> 2);
    const int wcol = 64 * (wave & 3);

    f32x4 acc[4][4] = {};
    const int lr = lane & 15;
    const int kg = lane >> 4;

    for (int kt = 0; kt < 16; ++kt) {
        const int k0 = kt << 5;
        {
            int c = wave * 64 + lane;
            const u16* g = A + (size_t)(m0 + (c >> 2)) * DM + k0 + ((c & 3) << 3);
            async_copy16(&sA[wave * 512], g);
        }
#pragma unroll
        for (int i = 0; i < 2; ++i) {
            int grp = i * 8 + wave;
            int c   = grp * 64 + lane;
            const u16* g = Wt + (size_t)(n0 + (c >> 2)) * DM + k0 + ((c & 3) << 3);
            async_copy16(&sB[grp * 512], g);
        }
        __syncthreads();

        frag_ab af[4], bfr[4];
#pragma unroll
        for (int i = 0; i < 4; ++i)
            af[i] = *(const frag_ab*)&sA[(wrow + i * 16 + lr) * 32 + kg * 8];
#pragma unroll
        for (int j = 0; j < 4; ++j)
            bfr[j] = *(const frag_ab*)&sB[(wcol + j * 16 + lr) * 32 + kg * 8];
#pragma unroll
        for (int i = 0; i < 4; ++i)
#pragma unroll
            for (int j = 0; j < 4; ++j)
                acc[i][j] = __builtin_amdgcn_mfma_f32_16x16x32_bf16(
                    af[i], bfr[j], acc[i][j], 0, 0, 0);
        __syncthreads();
    }

    const int crow0 = (lane >> 4) * 4;
#pragma unroll
    for (int i = 0; i < 4; ++i) {
#pragma unroll
        for (int j = 0; j < 4; ++j) {
            const int col = n0 + wcol + j * 16 + lr;
            const float bv = bias[col];
#pragma unroll
            for (int r = 0; r < 4; ++r) {
                const int row = m0 + wrow + i * 16 + crow0 + r;
                C[(size_t)row * 512 + col] = acc[i][j][r] + bv;
            }
        }
    }
}

// ---------------------------------------------------------------------------
// One-shot prep: cast q_in/kv_in f32->bf16, pack weights, concat biases.
// ---------------------------------------------------------------------------
__global__ __launch_bounds__(256) void prep_all(
    const float* __restrict__ q_in, const float* __restrict__ kv_in,
    const float* __restrict__ Wq, const float* __restrict__ Woff,
    const float* __restrict__ Wa, const float* __restrict__ Wk,
    const float* __restrict__ Wv, const float* __restrict__ Wo,
    const float* __restrict__ bq, const float* __restrict__ boff,
    const float* __restrict__ ba, const float* __restrict__ bk,
    const float* __restrict__ bv,
    u16* __restrict__ qb, u16* __restrict__ kvb,
    u16* __restrict__ Wcat1, u16* __restrict__ Wcat2, u16* __restrict__ Wob,
    float* __restrict__ bcat1, float* __restrict__ bcat2, int n4)
{
    const int W4  = 65536;   // 512*512/4
    const int W4s = 4096;    // 32*512/4
    int tid = blockIdx.x * 256 + threadIdx.x;
    if (tid < 2 * n4 + 4 * W4 + 2 * W4s) {
        const float* src; u16* dst; int off;
        int t = tid;
        if (t < n4)                    { src = q_in;  dst = qb;              off = t; }
        else if ((t -= n4) < n4)       { src = kv_in; dst = kvb;             off = t; }
        else if ((t -= n4) < W4)       { src = Wq;    dst = Wcat1;           off = t; }
        else if ((t -= W4) < W4s)      { src = Woff;  dst = Wcat1 + 262144;  off = t; }
        else if ((t -= W4s) < W4s)     { src = Wa;    dst = Wcat1 + 278528;  off = t; }
        else if ((t -= W4s) < W4)      { src = Wk;    dst = Wcat2;           off = t; }
        else if ((t -= W4) < W4)       { src = Wv;    dst = Wcat2 + 262144;  off = t; }
        else                           { src = Wo;    dst = Wob;             off = t - W4; }
        float4 v = ((const float4*)src)[off];
        ushort4 o;
        o.x = f2b(v.x); o.y = f2b(v.y); o.z = f2b(v.z); o.w = f2b(v.w);
        ((ushort4*)dst)[off] = o;
    } else {
        int j = tid - (2 * n4 + 4 * W4 + 2 * W4s);
        if (j < 576) {
            bcat1[j] = (j < 512) ? bq[j] : (j < 544 ? boff[j - 512] : ba[j - 544]);
        } else if (j < 1600) {
            int j2 = j - 576;
            bcat2[j2] = (j2 < 512) ? bk[j2] : bv[j2 - 512];
        }
    }
}

// ---------------------------------------------------------------------------
// Banded deformable attention. One wave per (b, h, 16-query block).
// k|v fused buffer: row stride 1024, k at cols 0..511, v at 512..1023.
// ---------------------------------------------------------------------------
__global__ __launch_bounds__(256) void deform_attn_band(
    const u16* __restrict__ q, const u16* __restrict__ kv,
    const float* __restrict__ offlog, u16* __restrict__ out, int B, int L)
{
    __shared__ u16  sVt[4][64 * 40];
    __shared__ float sS[4][16 * 36];
    __shared__ float sW[4][16 * 36];

    const int wave = threadIdx.x >> 6;
    const int lane = threadIdx.x & 63;
    const int gw = blockIdx.x * 4 + wave;     // over B*NH*(L/16)
    const int nlb = L >> 4;
    const int lblk = gw % nlb;
    const int bh = gw / nlb;
    const int h = bh % NH;
    const int b = bh / NH;
    const int l0 = lblk << 4;

    u16*  __restrict__ vt = sVt[wave];
    float* __restrict__ Ss = sS[wave];
    float* __restrict__ Ws = sW[wave];

    const size_t brow = (size_t)b * L;
    const int headoff = h * DD;

    const int l_loc = lane >> 2, p = lane & 3;
    const size_t obase = (brow + l0 + l_loc) * 64 + h * 4 + p;
    const float offv  = offlog[obase];
    const float logit = offlog[obase + 32];

    const int fr = lane & 15, kg = lane >> 4;

    const u16* qrow = q + (brow + l0 + fr) * DM + headoff;
    frag_ab qf0 = *(const frag_ab*)(qrow + kg * 8);
    frag_ab qf1 = *(const frag_ab*)(qrow + kg * 8 + 32);

    frag_ab kf[2][2];
#pragma unroll
    for (int jf = 0; jf < 2; ++jf) {
        int rr = l0 - 8 + jf * 16 + fr;
        rr = min(max(rr, 0), L - 1);
        const u16* krow = kv + (brow + rr) * 1024 + headoff;
        kf[jf][0] = *(const frag_ab*)(krow + kg * 8);
        kf[jf][1] = *(const frag_ab*)(krow + kg * 8 + 32);
    }

    const int vr = lane & 31, vd0 = (lane >> 5) * 32;
    int vrr = min(max(l0 - 8 + vr, 0), L - 1);
    const u16* vrow = kv + (brow + vrr) * 1024 + 512 + headoff + vd0;
    frag_ab vl[4];
#pragma unroll
    for (int i = 0; i < 4; ++i)
        vl[i] = *(const frag_ab*)(vrow + i * 8);

    f32x4 accS[2] = {};
#pragma unroll
    for (int jf = 0; jf < 2; ++jf) {
        accS[jf] = __builtin_amdgcn_mfma_f32_16x16x32_bf16(qf0, kf[jf][0], accS[jf], 0, 0, 0);
        accS[jf] = __builtin_amdgcn_mfma_f32_16x16x32_bf16(qf1, kf[jf][1], accS[jf], 0, 0, 0);
    }

#pragma unroll
    for (int i = 0; i < 4; ++i)
#pragma unroll
        for (int j = 0; j < 8; ++j)
            vt[(vd0 + i * 8 + j) * 40 + vr] = (u16)vl[i][j];

#pragma unroll
    for (int jf = 0; jf < 2; ++jf)
#pragma unroll
        for (int r = 0; r < 4; ++r)
            Ss[(kg * 4 + r) * 36 + jf * 16 + fr] = accS[jf][r];

#pragma unroll
    for (int i = 0; i < 9; ++i)
        Ws[lane + 64 * i] = 0.f;

    __syncthreads();

    float pos = fminf(fmaxf((float)(l0 + l_loc) + offv, 0.f), (float)(L - 1));
    float ff = floorf(pos);
    int i0 = (int)ff;
    float fw = pos - ff;
    int c0 = i0 - (l0 - 8);
    c0 = min(max(c0, 0), 30);
    float S0 = Ss[l_loc * 36 + c0];
    float S1 = Ss[l_loc * 36 + c0 + 1];
    float t = (S0 + fw * (S1 - S0)) * 0.125f + logit;
    float m1 = fmaxf(t, __shfl_xor(t, 1));
    float mx = fmaxf(m1, __shfl_xor(m1, 2));
    float e = __expf(t - mx);
    float s1 = e + __shfl_xor(e, 1);
    float ssum = s1 + __shfl_xor(s1, 2);
    float wgt = e * __builtin_amdgcn_rcpf(ssum);
    atomicAdd(&Ws[l_loc * 36 + c0], (1.f - fw) * wgt);
    atomicAdd(&Ws[l_loc * 36 + c0 + 1], fw * wgt);

    __syncthreads();

    float4 w0 = *(const float4*)&Ws[fr * 36 + kg * 8];
    float4 w1 = *(const float4*)&Ws[fr * 36 + kg * 8 + 4];
    frag_ab wf;
    wf[0] = (short)f2b(w0.x); wf[1] = (short)f2b(w0.y);
    wf[2] = (short)f2b(w0.z); wf[3] = (short)f2b(w0.w);
    wf[4] = (short)f2b(w1.x); wf[5] = (short)f2b(w1.y);
    wf[6] = (short)f2b(w1.z); wf[7] = (short)f2b(w1.w);

#pragma unroll
    for (int md = 0; md < 4; ++md) {
        frag_ab af = *(const frag_ab*)&vt[(md * 16 + fr) * 40 + kg * 8];
        f32x4 o = {};
        o = __builtin_amdgcn_mfma_f32_16x16x32_bf16(af, wf, o, 0, 0, 0);
        ushort4 pk;
        pk.x = f2b(o[0]); pk.y = f2b(o[1]); pk.z = f2b(o[2]); pk.w = f2b(o[3]);
        *(ushort4*)&out[(brow + l0 + fr) * DM + headoff + md * 16 + kg * 4] = pk;
    }
}

// ---------------------------------------------------------------------------
extern "C" void kernel_launch(void* const* d_in, const int* in_sizes, int n_in,
                              void* d_out, int out_size, void* d_ws, size_t ws_size,
                              hipStream_t stream) {
    const float* q_in  = (const float*)d_in[0];
    const float* kv_in = (const float*)d_in[1];
    const float* Wq = (const float*)d_in[2];  const float* bq = (const float*)d_in[3];
    const float* Wk = (const float*)d_in[4];  const float* bk = (const float*)d_in[5];
    const float* Wv = (const float*)d_in[6];  const float* bv = (const float*)d_in[7];
    const float* Woff=(const float*)d_in[8];  const float* boff=(const float*)d_in[9];
    const float* Wa = (const float*)d_in[10]; const float* ba = (const float*)d_in[11];
    const float* Wo = (const float*)d_in[12]; const float* bo = (const float*)d_in[13];

    const int M = in_sizes[0] / DM;     // B*L = 16384
    const int L = 4096;
    const int B = M / L;

    char* p = (char*)d_ws;
    u16* qb     = (u16*)p;               p += (size_t)M * DM * 2;     // attn out later
    u16* kvb    = (u16*)p;               p += (size_t)M * DM * 2;
    u16* Wcat1  = (u16*)p;               p += (size_t)768 * DM * 2;   // 576 used; pad for OOB staging
    u16* Wcat2  = (u16*)p;               p += (size_t)1024 * DM * 2;
    u16* Wob    = (u16*)p;               p += (size_t)DM * DM * 2;
    float* bcat1= (float*)p;             p += 640 * 4;
    float* bcat2= (float*)p;             p += 1024 * 4;
    u16* q_ws   = (u16*)p;               p += (size_t)M * DM * 2;
    u16* kv_ws  = (u16*)p;               p += (size_t)M * 1024 * 2;   // k|v fused
    float* offlog = (float*)p;           p += (size_t)M * 64 * 4;

    const int n4 = (M * DM) / 4;
    const int prep_threads = 2 * n4 + 4 * 65536 + 2 * 4096 + 1600;

    hipLaunchKernelGGL(prep_all, dim3((prep_threads + 255) / 256), dim3(256), 0, stream,
                       q_in, kv_in, Wq, Woff, Wa, Wk, Wv, Wo,
                       bq, boff, ba, bk, bv,
                       qb, kvb, Wcat1, Wcat2, Wob, bcat1, bcat2, n4);

    // merged projections: y<3 -> q/off/a (N=576), y>=3 -> k|v (N=1024)
    hipLaunchKernelGGL(proj_gemm, dim3(M / 128, 7), dim3(512), 0, stream,
                       qb, kvb, Wcat1, Wcat2, bcat1, bcat2,
                       q_ws, offlog, kv_ws);

    // banded attention: 1 wave per (b,h,16 queries); out -> qb
    int nwaves = B * NH * (L / 16);
    hipLaunchKernelGGL(deform_attn_band, dim3(nwaves / 4), dim3(256), 0, stream,
                       q_ws, kv_ws, offlog, qb, B, L);

    // output projection -> fp32 d_out
    hipLaunchKernelGGL(out_gemm, dim3(M / 128, 2), dim3(512), 0, stream,
                       qb, Wob, bo, (float*)d_out);
}

// Round 7
// 217.288 us; speedup vs baseline: 1.2749x; 1.0615x over previous
//
#include <hip/hip_runtime.h>
#include <hip/hip_bf16.h>
#include <math.h>

#define NH 8
#define NP 4
#define DD 64
#define DM 512

typedef unsigned short u16;
typedef unsigned int u32;

using frag_ab = __attribute__((ext_vector_type(8))) short;  // 8 bf16 (4 VGPRs)
using f32x4   = __attribute__((ext_vector_type(4))) float;  // 4 fp32 acc

__device__ __forceinline__ u16 f2b(float f) {               // fp32 -> bf16 (RNE)
    u32 u = __float_as_uint(f);
    u32 r = (u + 0x7FFFu + ((u >> 16) & 1u)) >> 16;
    return (u16)r;
}
__device__ __forceinline__ u32 pk2(float x, float y) {      // 2xf32 -> packed bf16x2 (RNE)
    float2 t; t.x = x; t.y = y;
    __hip_bfloat162 h = __float22bfloat162_rn(t);
    return *(u32*)&h;
}

#define GLOBAL_AS __attribute__((address_space(1)))
#define LDS_AS    __attribute__((address_space(3)))
__device__ __forceinline__ void async_copy16(void* lds, const void* g) {
    __builtin_amdgcn_global_load_lds((const GLOBAL_AS u32*)g, (LDS_AS u32*)lds, 16, 0, 0);
}

// ---------------------------------------------------------------------------
// Merged projection GEMM.  BM=BN=128, BK=32, 256 threads (4 waves),
// wave tile 64x64 (acc[4][4]).  A is **fp32** (q_in / kv_in), converted to
// bf16 during LDS staging (v_cvt_pk_bf16_f32 + ds_write_b128).  B is bf16
// staged via global_load_lds.
//   blockIdx.y < 5 : C = q_in @ Wcat1^T + bcat1 (N=576; cols<512 -> q_ws bf16,
//                    512<=cols<576 -> offlog f32 ld64; frags >=576 skipped)
//   blockIdx.y >= 5: C = kv_in @ Wcat2^T + bcat2 (N=1024 -> kv_ws bf16 ld1024)
// ---------------------------------------------------------------------------
__global__ __launch_bounds__(256) void proj_gemm(
    const float* __restrict__ q_in, const float* __restrict__ kv_in,
    const u16* __restrict__ Wcat1, const u16* __restrict__ Wcat2,
    const float* __restrict__ bcat1, const float* __restrict__ bcat2,
    u16* __restrict__ q_ws, float* __restrict__ offlog,
    u16* __restrict__ kv_ws)
{
    constexpr int BM = 128, BK = 32;
    __shared__ u16 sA[BM * BK];
    __shared__ u16 sB[BM * BK];

    const int tid  = threadIdx.x;
    const int wave = tid >> 6;
    const int lane = tid & 63;
    const int m0 = blockIdx.x * BM;
    const bool is_q = blockIdx.y < 5;
    const int n0 = (is_q ? blockIdx.y : blockIdx.y - 5) * BM;
    const int Ncur = is_q ? 576 : 1024;
    const float* __restrict__ A   = is_q ? q_in : kv_in;
    const u16* __restrict__ Wt    = is_q ? Wcat1 : Wcat2;
    const float* __restrict__ bias = is_q ? bcat1 : bcat2;

    const int wrow = 64 * (wave >> 1);
    const int wcol = 64 * (wave & 1);

    f32x4 acc[4][4] = {};
    const int lr = lane & 15;
    const int kg = lane >> 4;

    for (int kt = 0; kt < 16; ++kt) {
        const int k0 = kt << 5;
        // ---- A: fp32 global -> cvt -> LDS (bf16), 512 chunks of 8 elems ----
#pragma unroll
        for (int i = 0; i < 2; ++i) {
            int c = i * 256 + tid;                // 0..511
            int row = c >> 2, col8 = (c & 3) << 3;
            const float* g = A + (size_t)(m0 + row) * DM + k0 + col8;
            float4 a = *(const float4*)g;
            float4 b = *(const float4*)(g + 4);
            uint4 w;
            w.x = pk2(a.x, a.y); w.y = pk2(a.z, a.w);
            w.z = pk2(b.x, b.y); w.w = pk2(b.z, b.w);
            *(uint4*)&sA[(row << 5) + col8] = w;
        }
        // ---- B: bf16 async, 8 groups of 1 KB ----
#pragma unroll
        for (int i = 0; i < 2; ++i) {
            int grp = i * 4 + wave;
            int c   = grp * 64 + lane;
            const u16* g = Wt + (size_t)(n0 + (c >> 2)) * DM + k0 + ((c & 3) << 3);
            async_copy16(&sB[grp * 512], g);
        }
        __syncthreads();

        frag_ab af[4], bfr[4];
#pragma unroll
        for (int i = 0; i < 4; ++i)
            af[i] = *(const frag_ab*)&sA[(wrow + i * 16 + lr) * 32 + kg * 8];
#pragma unroll
        for (int j = 0; j < 4; ++j)
            bfr[j] = *(const frag_ab*)&sB[(wcol + j * 16 + lr) * 32 + kg * 8];
#pragma unroll
        for (int i = 0; i < 4; ++i)
#pragma unroll
            for (int j = 0; j < 4; ++j)
                acc[i][j] = __builtin_amdgcn_mfma_f32_16x16x32_bf16(
                    af[i], bfr[j], acc[i][j], 0, 0, 0);
        __syncthreads();
    }

    const int crow0 = (lane >> 4) * 4;
#pragma unroll
    for (int i = 0; i < 4; ++i) {
#pragma unroll
        for (int j = 0; j < 4; ++j) {
            const int colbase = n0 + wcol + j * 16;
            if (colbase >= Ncur) continue;        // wave-uniform tail skip
            const int col = colbase + lr;
            const float bv = bias[col];
#pragma unroll
            for (int r = 0; r < 4; ++r) {
                const int row = m0 + wrow + i * 16 + crow0 + r;
                const float val = acc[i][j][r] + bv;
                if (!is_q)
                    kv_ws[(size_t)row * 1024 + col] = f2b(val);
                else if (colbase < 512)
                    q_ws[(size_t)row * 512 + col] = f2b(val);
                else
                    offlog[(size_t)row * 64 + (col - 512)] = val;
            }
        }
    }
}

// ---------------------------------------------------------------------------
// Output GEMM: C(f32) = A(bf16, Mx512) @ Wob^T + bo.  Proven R3 shape:
// 256 threads, BM=BN=128, async staging both operands.
// ---------------------------------------------------------------------------
__global__ __launch_bounds__(256) void out_gemm(
    const u16* __restrict__ A, const u16* __restrict__ Wt,
    const float* __restrict__ bias, float* __restrict__ C)
{
    constexpr int BM = 128, BK = 32;
    __shared__ u16 sA[BM * BK];
    __shared__ u16 sB[BM * BK];

    const int tid  = threadIdx.x;
    const int wave = tid >> 6;
    const int lane = tid & 63;
    const int m0 = blockIdx.x * BM;
    const int n0 = blockIdx.y * BM;

    const int wrow = 64 * (wave >> 1);
    const int wcol = 64 * (wave & 1);

    f32x4 acc[4][4] = {};
    const int lr = lane & 15;
    const int kg = lane >> 4;

    for (int kt = 0; kt < 16; ++kt) {
        const int k0 = kt << 5;
#pragma unroll
        for (int i = 0; i < 2; ++i) {
            int grp = i * 4 + wave;
            int c   = grp * 64 + lane;
            const u16* g = A + (size_t)(m0 + (c >> 2)) * DM + k0 + ((c & 3) << 3);
            async_copy16(&sA[grp * 512], g);
        }
#pragma unroll
        for (int i = 0; i < 2; ++i) {
            int grp = i * 4 + wave;
            int c   = grp * 64 + lane;
            const u16* g = Wt + (size_t)(n0 + (c >> 2)) * DM + k0 + ((c & 3) << 3);
            async_copy16(&sB[grp * 512], g);
        }
        __syncthreads();

        frag_ab af[4], bfr[4];
#pragma unroll
        for (int i = 0; i < 4; ++i)
            af[i] = *(const frag_ab*)&sA[(wrow + i * 16 + lr) * 32 + kg * 8];
#pragma unroll
        for (int j = 0; j < 4; ++j)
            bfr[j] = *(const frag_ab*)&sB[(wcol + j * 16 + lr) * 32 + kg * 8];
#pragma unroll
        for (int i = 0; i < 4; ++i)
#pragma unroll
            for (int j = 0; j < 4; ++j)
                acc[i][j] = __builtin_amdgcn_mfma_f32_16x16x32_bf16(
                    af[i], bfr[j], acc[i][j], 0, 0, 0);
        __syncthreads();
    }

    const int crow0 = (lane >> 4) * 4;
#pragma unroll
    for (int i = 0; i < 4; ++i) {
#pragma unroll
        for (int j = 0; j < 4; ++j) {
            const int col = n0 + wcol + j * 16 + lr;
            const float bv = bias[col];
#pragma unroll
            for (int r = 0; r < 4; ++r) {
                const int row = m0 + wrow + i * 16 + crow0 + r;
                C[(size_t)row * 512 + col] = acc[i][j][r] + bv;
            }
        }
    }
}

// ---------------------------------------------------------------------------
// Weight/bias prep only (inputs no longer pre-cast).
//   Wcat1 = [Wq; Woff; Wa] (576x512, alloc 768)   bcat1 = [bq; boff; ba]
//   Wcat2 = [Wk; Wv]       (1024x512)             bcat2 = [bk; bv]
//   Wob   = Wo
// ---------------------------------------------------------------------------
__global__ __launch_bounds__(256) void prep_weights(
    const float* __restrict__ Wq, const float* __restrict__ Woff,
    const float* __restrict__ Wa, const float* __restrict__ Wk,
    const float* __restrict__ Wv, const float* __restrict__ Wo,
    const float* __restrict__ bq, const float* __restrict__ boff,
    const float* __restrict__ ba, const float* __restrict__ bk,
    const float* __restrict__ bv,
    u16* __restrict__ Wcat1, u16* __restrict__ Wcat2, u16* __restrict__ Wob,
    float* __restrict__ bcat1, float* __restrict__ bcat2)
{
    const int W4  = 65536;   // 512*512/4
    const int W4s = 4096;    // 32*512/4
    int tid = blockIdx.x * 256 + threadIdx.x;
    if (tid < 4 * W4 + 2 * W4s) {
        const float* src; u16* dst; int off;
        int t = tid;
        if (t < W4)                    { src = Wq;    dst = Wcat1;           off = t; }
        else if ((t -= W4) < W4s)      { src = Woff;  dst = Wcat1 + 262144;  off = t; }
        else if ((t -= W4s) < W4s)     { src = Wa;    dst = Wcat1 + 278528;  off = t; }
        else if ((t -= W4s) < W4)      { src = Wk;    dst = Wcat2;           off = t; }
        else if ((t -= W4) < W4)       { src = Wv;    dst = Wcat2 + 262144;  off = t; }
        else                           { src = Wo;    dst = Wob;             off = t - W4; }
        float4 v = ((const float4*)src)[off];
        ushort4 o;
        o.x = f2b(v.x); o.y = f2b(v.y); o.z = f2b(v.z); o.w = f2b(v.w);
        ((ushort4*)dst)[off] = o;
    } else {
        int j = tid - (4 * W4 + 2 * W4s);
        if (j < 576) {
            bcat1[j] = (j < 512) ? bq[j] : (j < 544 ? boff[j - 512] : ba[j - 544]);
        } else if (j < 1600) {
            int j2 = j - 576;
            bcat2[j2] = (j2 < 512) ? bk[j2] : bv[j2 - 512];
        }
    }
}

// ---------------------------------------------------------------------------
// Banded deformable attention. One wave per (b, h, 16-query block).
// k|v fused buffer: row stride 1024, k at cols 0..511, v at 512..1023.
// ---------------------------------------------------------------------------
__global__ __launch_bounds__(256) void deform_attn_band(
    const u16* __restrict__ q, const u16* __restrict__ kv,
    const float* __restrict__ offlog, u16* __restrict__ out, int B, int L)
{
    __shared__ u16  sVt[4][64 * 40];
    __shared__ float sS[4][16 * 36];
    __shared__ float sW[4][16 * 36];

    const int wave = threadIdx.x >> 6;
    const int lane = threadIdx.x & 63;
    const int gw = blockIdx.x * 4 + wave;     // over B*NH*(L/16)
    const int nlb = L >> 4;
    const int lblk = gw % nlb;
    const int bh = gw / nlb;
    const int h = bh % NH;
    const int b = bh / NH;
    const int l0 = lblk << 4;

    u16*  __restrict__ vt = sVt[wave];
    float* __restrict__ Ss = sS[wave];
    float* __restrict__ Ws = sW[wave];

    const size_t brow = (size_t)b * L;
    const int headoff = h * DD;

    const int l_loc = lane >> 2, p = lane & 3;
    const size_t obase = (brow + l0 + l_loc) * 64 + h * 4 + p;
    const float offv  = offlog[obase];
    const float logit = offlog[obase + 32];

    const int fr = lane & 15, kg = lane >> 4;

    const u16* qrow = q + (brow + l0 + fr) * DM + headoff;
    frag_ab qf0 = *(const frag_ab*)(qrow + kg * 8);
    frag_ab qf1 = *(const frag_ab*)(qrow + kg * 8 + 32);

    frag_ab kf[2][2];
#pragma unroll
    for (int jf = 0; jf < 2; ++jf) {
        int rr = l0 - 8 + jf * 16 + fr;
        rr = min(max(rr, 0), L - 1);
        const u16* krow = kv + (brow + rr) * 1024 + headoff;
        kf[jf][0] = *(const frag_ab*)(krow + kg * 8);
        kf[jf][1] = *(const frag_ab*)(krow + kg * 8 + 32);
    }

    const int vr = lane & 31, vd0 = (lane >> 5) * 32;
    int vrr = min(max(l0 - 8 + vr, 0), L - 1);
    const u16* vrow = kv + (brow + vrr) * 1024 + 512 + headoff + vd0;
    frag_ab vl[4];
#pragma unroll
    for (int i = 0; i < 4; ++i)
        vl[i] = *(const frag_ab*)(vrow + i * 8);

    f32x4 accS[2] = {};
#pragma unroll
    for (int jf = 0; jf < 2; ++jf) {
        accS[jf] = __builtin_amdgcn_mfma_f32_16x16x32_bf16(qf0, kf[jf][0], accS[jf], 0, 0, 0);
        accS[jf] = __builtin_amdgcn_mfma_f32_16x16x32_bf16(qf1, kf[jf][1], accS[jf], 0, 0, 0);
    }

#pragma unroll
    for (int i = 0; i < 4; ++i)
#pragma unroll
        for (int j = 0; j < 8; ++j)
            vt[(vd0 + i * 8 + j) * 40 + vr] = (u16)vl[i][j];

#pragma unroll
    for (int jf = 0; jf < 2; ++jf)
#pragma unroll
        for (int r = 0; r < 4; ++r)
            Ss[(kg * 4 + r) * 36 + jf * 16 + fr] = accS[jf][r];

#pragma unroll
    for (int i = 0; i < 9; ++i)
        Ws[lane + 64 * i] = 0.f;

    __syncthreads();

    float pos = fminf(fmaxf((float)(l0 + l_loc) + offv, 0.f), (float)(L - 1));
    float ff = floorf(pos);
    int i0 = (int)ff;
    float fw = pos - ff;
    int c0 = i0 - (l0 - 8);
    c0 = min(max(c0, 0), 30);
    float S0 = Ss[l_loc * 36 + c0];
    float S1 = Ss[l_loc * 36 + c0 + 1];
    float t = (S0 + fw * (S1 - S0)) * 0.125f + logit;
    float m1 = fmaxf(t, __shfl_xor(t, 1));
    float mx = fmaxf(m1, __shfl_xor(m1, 2));
    float e = __expf(t - mx);
    float s1 = e + __shfl_xor(e, 1);
    float ssum = s1 + __shfl_xor(s1, 2);
    float wgt = e * __builtin_amdgcn_rcpf(ssum);
    atomicAdd(&Ws[l_loc * 36 + c0], (1.f - fw) * wgt);
    atomicAdd(&Ws[l_loc * 36 + c0 + 1], fw * wgt);

    __syncthreads();

    float4 w0 = *(const float4*)&Ws[fr * 36 + kg * 8];
    float4 w1 = *(const float4*)&Ws[fr * 36 + kg * 8 + 4];
    frag_ab wf;
    wf[0] = (short)f2b(w0.x); wf[1] = (short)f2b(w0.y);
    wf[2] = (short)f2b(w0.z); wf[3] = (short)f2b(w0.w);
    wf[4] = (short)f2b(w1.x); wf[5] = (short)f2b(w1.y);
    wf[6] = (short)f2b(w1.z); wf[7] = (short)f2b(w1.w);

#pragma unroll
    for (int md = 0; md < 4; ++md) {
        frag_ab af = *(const frag_ab*)&vt[(md * 16 + fr) * 40 + kg * 8];
        f32x4 o = {};
        o = __builtin_amdgcn_mfma_f32_16x16x32_bf16(af, wf, o, 0, 0, 0);
        ushort4 pk;
        pk.x = f2b(o[0]); pk.y = f2b(o[1]); pk.z = f2b(o[2]); pk.w = f2b(o[3]);
        *(ushort4*)&out[(brow + l0 + fr) * DM + headoff + md * 16 + kg * 4] = pk;
    }
}

// ---------------------------------------------------------------------------
extern "C" void kernel_launch(void* const* d_in, const int* in_sizes, int n_in,
                              void* d_out, int out_size, void* d_ws, size_t ws_size,
                              hipStream_t stream) {
    const float* q_in  = (const float*)d_in[0];
    const float* kv_in = (const float*)d_in[1];
    const float* Wq = (const float*)d_in[2];  const float* bq = (const float*)d_in[3];
    const float* Wk = (const float*)d_in[4];  const float* bk = (const float*)d_in[5];
    const float* Wv = (const float*)d_in[6];  const float* bv = (const float*)d_in[7];
    const float* Woff=(const float*)d_in[8];  const float* boff=(const float*)d_in[9];
    const float* Wa = (const float*)d_in[10]; const float* ba = (const float*)d_in[11];
    const float* Wo = (const float*)d_in[12]; const float* bo = (const float*)d_in[13];

    const int M = in_sizes[0] / DM;     // B*L = 16384
    const int L = 4096;
    const int B = M / L;

    char* p = (char*)d_ws;
    u16* attn_o = (u16*)p;               p += (size_t)M * DM * 2;     // attention output
    u16* Wcat1  = (u16*)p;               p += (size_t)768 * DM * 2;   // 640 used; pad for OOB staging
    u16* Wcat2  = (u16*)p;               p += (size_t)1024 * DM * 2;
    u16* Wob    = (u16*)p;               p += (size_t)DM * DM * 2;
    float* bcat1= (float*)p;             p += 640 * 4;
    float* bcat2= (float*)p;             p += 1024 * 4;
    u16* q_ws   = (u16*)p;               p += (size_t)M * DM * 2;
    u16* kv_ws  = (u16*)p;               p += (size_t)M * 1024 * 2;   // k|v fused
    float* offlog = (float*)p;           p += (size_t)M * 64 * 4;

    const int prep_threads = 4 * 65536 + 2 * 4096 + 1600;
    hipLaunchKernelGGL(prep_weights, dim3((prep_threads + 255) / 256), dim3(256), 0, stream,
                       Wq, Woff, Wa, Wk, Wv, Wo, bq, boff, ba, bk, bv,
                       Wcat1, Wcat2, Wob, bcat1, bcat2);

    // merged projections (fp32 A in-kernel cast): y<5 -> q/off/a, y>=5 -> k|v
    hipLaunchKernelGGL(proj_gemm, dim3(M / 128, 13), dim3(256), 0, stream,
                       q_in, kv_in, Wcat1, Wcat2, bcat1, bcat2,
                       q_ws, offlog, kv_ws);

    // banded attention: 1 wave per (b,h,16 queries)
    int nwaves = B * NH * (L / 16);
    hipLaunchKernelGGL(deform_attn_band, dim3(nwaves / 4), dim3(256), 0, stream,
                       q_ws, kv_ws, offlog, attn_o, B, L);

    // output projection -> fp32 d_out
    hipLaunchKernelGGL(out_gemm, dim3(M / 128, 4), dim3(256), 0, stream,
                       attn_o, Wob, bo, (float*)d_out);
}